// Round 5
// baseline (66.008 us; speedup 1.0000x reference)
//
#include <hip/hip_runtime.h>
#include <hip/hip_bf16.h>

// ---------------------------------------------------------------------------
// TT-adapter fused kernel for MI355X (gfx950)
// out = hs + gelu(hs @ W_down + b_down) @ W_up + b_up
// W_down [768,64], W_up [64,768] reconstructed from rank-5 TT cores.
//
// Kernel 0: build bf16 weights in MFMA-fragment-ready layout in d_ws.
// Kernel 1: 2048 blocks x 256 thr (4 waves), 16 rows/block, 8 blocks/CU:
//   Phase 1: down-GEMM K-SPLIT 4 ways across waves (192 K each, direct
//            global->VGPR loads), partial-acc reduce via padded LDS.
//   Phase 2: up-GEMM col-split (12 tiles/wave), SWAPPED operands so the
//            D fragment is lane-row-local -> f32x4 residual re-read (L3)
//            + f32x4 store. 32 waves/CU for latency hiding.
// ---------------------------------------------------------------------------

typedef __attribute__((ext_vector_type(8))) short bf16x8;
typedef __attribute__((ext_vector_type(4))) float f32x4;

__device__ __forceinline__ unsigned short f2bf(float f) {
    union { float f; unsigned u; } v; v.f = f;
    unsigned r = (v.u + 0x7FFFu + ((v.u >> 16) & 1u)) >> 16;
    return (unsigned short)r;
}

// Staged TT contraction for one matrix entry (cores in LDS).
__device__ __forceinline__ float tt_entry(
    const float* c0, const float* c1, const float* c2,
    const float* c3, const float* c4,
    int i0, int i1, int i2, int i3, int i4)
{
    float v1[5], v2[5], v3[5];
#pragma unroll
    for (int r2 = 0; r2 < 5; ++r2) {
        float s = 0.f;
#pragma unroll
        for (int r1 = 0; r1 < 5; ++r1)
            s += c0[i0 * 5 + r1] * c1[(r1 * 8 + i1) * 5 + r2];
        v1[r2] = s;
    }
#pragma unroll
    for (int r3 = 0; r3 < 5; ++r3) {
        float s = 0.f;
#pragma unroll
        for (int r2 = 0; r2 < 5; ++r2)
            s += v1[r2] * c2[(r2 * 12 + i2) * 5 + r3];
        v2[r3] = s;
    }
#pragma unroll
    for (int r4 = 0; r4 < 5; ++r4) {
        float s = 0.f;
#pragma unroll
        for (int r3 = 0; r3 < 5; ++r3)
            s += v2[r3] * c3[(r3 * 8 + i3) * 5 + r4];
        v3[r4] = s;
    }
    float w = 0.f;
#pragma unroll
    for (int r4 = 0; r4 < 5; ++r4)
        w += v3[r4] * c4[r4 * 8 + i4];
    return w;
}

// WdFrag[((ks*4+nt)*64 + lane)*8 + j] = Wd[ks*32 + (lane>>4)*8 + j][nt*16 + (lane&15)]
// WuFrag[((s*48+ht)*64 + lane)*8 + j] = Wu[s*32  + (lane>>4)*8 + j][ht*16 + (lane&15)]
//   (B-frag of Wu == A-frag of Wu^T, so the same buffer serves the swapped GEMM)
__global__ __launch_bounds__(256) void tt_build_frags(
    const float* __restrict__ d0, const float* __restrict__ d1,
    const float* __restrict__ d2, const float* __restrict__ d3,
    const float* __restrict__ d4,
    const float* __restrict__ u0, const float* __restrict__ u1,
    const float* __restrict__ u2, const float* __restrict__ u3,
    const float* __restrict__ u4,
    unsigned short* __restrict__ wdFrag, unsigned short* __restrict__ wuFrag)
{
    __shared__ float cs[1560];
    {
        const float* srcs[10] = { d0, d1, d2, d3, d4, u0, u1, u2, u3, u4 };
        const int sizes[10]   = { 40, 200, 300, 200, 40, 40, 200, 300, 200, 40 };
        const int offs[10]    = { 0, 40, 240, 540, 740, 780, 820, 1020, 1320, 1520 };
#pragma unroll
        for (int c = 0; c < 10; ++c)
            for (int i = threadIdx.x; i < sizes[c]; i += 256)
                cs[offs[c] + i] = srcs[c][i];
    }
    __syncthreads();

    int e = blockIdx.x * 256 + threadIdx.x;   // 0..98303
    bool isUp = (e >= 49152);
    int idx = isUp ? (e - 49152) : e;
    int j    = idx & 7;
    int lane = (idx >> 3) & 63;
    int tile = idx >> 9;                      // 0..95
    int kg = lane >> 4, ln = lane & 15;

    if (!isUp) {
        int ks = tile >> 2, nt = tile & 3;
        int k = ks * 32 + kg * 8 + j;
        int a = nt * 16 + ln;
        int i0 = k / 96, i1 = (k / 12) % 8, i2 = k % 12;
        int i3 = a >> 3, i4 = a & 7;
        float w = tt_entry(cs + 0, cs + 40, cs + 240, cs + 540, cs + 740,
                           i0, i1, i2, i3, i4);
        wdFrag[idx] = f2bf(w);
    } else {
        int s = tile / 48, ht = tile % 48;
        int aIn = s * 32 + kg * 8 + j;
        int h = ht * 16 + ln;
        int i0 = aIn >> 3, i1 = aIn & 7;
        int i2 = h / 64, i3 = (h >> 3) & 7, i4 = h & 7;
        float w = tt_entry(cs + 780, cs + 820, cs + 1020, cs + 1320, cs + 1520,
                           i0, i1, i2, i3, i4);
        wuFrag[idx] = f2bf(w);
    }
}

__device__ __forceinline__ bf16x8 cvt8(f32x4 a, f32x4 b) {
    union { bf16x8 v; __hip_bfloat162 h[4]; } r;
    r.h[0] = __float22bfloat162_rn(make_float2(a[0], a[1]));
    r.h[1] = __float22bfloat162_rn(make_float2(a[2], a[3]));
    r.h[2] = __float22bfloat162_rn(make_float2(b[0], b[1]));
    r.h[3] = __float22bfloat162_rn(make_float2(b[2], b[3]));
    return r.v;
}

// ---------------------------------------------------------------------------
// Fused kernel: 2048 blocks x 256 thr, 16 rows/block, K-split down-GEMM.
// LDS: part[4][4][16][17] f32 (17 KB, padded) + act 2 KB = 19.4 KB -> 8 blk/CU.
// __launch_bounds__(256,8): VGPR <= 64 -> 32 waves/CU.
// ---------------------------------------------------------------------------
__global__ __launch_bounds__(256, 8) void adapter_fused(
    const float* __restrict__ hs,
    const float* __restrict__ b_down,
    const float* __restrict__ b_up,
    const unsigned short* __restrict__ wdFrag,
    const unsigned short* __restrict__ wuFrag,
    float* __restrict__ out)
{
    __shared__ float part[4][4][16][17];   // [wave][nt][row][col(+pad)]
    __shared__ char  act_s[2048];          // bf16 16x64, XOR-swizzled

    const int t    = threadIdx.x;
    const int lane = t & 63;
    const int w    = t >> 6;
    const int ln   = lane & 15;
    const int kg   = lane >> 4;

    const int wrow0 = blockIdx.x * 16;

    // ---------------- Phase 1: down GEMM, K-split 4 ways ----------------
    const float* hsrow = hs + (size_t)(wrow0 + ln) * 768 + w * 192 + kg * 8;

    f32x4 acc[4];
#pragma unroll
    for (int nt = 0; nt < 4; ++nt) acc[nt] = (f32x4){0.f, 0.f, 0.f, 0.f};

#pragma unroll
    for (int ks = 0; ks < 6; ++ks) {
        f32x4 fa = *(const f32x4*)(hsrow + ks * 32);
        f32x4 fb = *(const f32x4*)(hsrow + ks * 32 + 4);
        bf16x8 afrag = cvt8(fa, fb);
        const int ksg = w * 6 + ks;            // global K-tile 0..23
#pragma unroll
        for (int nt = 0; nt < 4; ++nt) {
            bf16x8 bfrag = *(const bf16x8*)(wdFrag + (ksg * 4 + nt) * 512 + lane * 8);
            acc[nt] = __builtin_amdgcn_mfma_f32_16x16x32_bf16(afrag, bfrag, acc[nt], 0, 0, 0);
        }
    }

    // write partial acc tiles (D layout: col=ln, row=kg*4+r)
#pragma unroll
    for (int nt = 0; nt < 4; ++nt)
#pragma unroll
        for (int r = 0; r < 4; ++r)
            part[w][nt][kg * 4 + r][ln] = acc[nt][r];
    __syncthreads();

    // reduce: wave w owns col-tile nt=w; sum over the 4 K-partials
    f32x4 facc = (f32x4){0.f, 0.f, 0.f, 0.f};
#pragma unroll
    for (int v = 0; v < 4; ++v)
#pragma unroll
        for (int r = 0; r < 4; ++r)
            facc[r] += part[v][w][kg * 4 + r][ln];

    // bias + exact gelu -> act (bf16, XOR-swizzled rows)
    {
        const float bd = b_down[w * 16 + ln];
#pragma unroll
        for (int r = 0; r < 4; ++r) {
            const int rr = kg * 4 + r;                  // act row (local)
            float x = facc[r] + bd;
            float g = 0.5f * x * (1.0f + erff(x * 0.70710678118654752f));
            unsigned off = ((unsigned)(rr * 128 + (w * 16 + ln) * 2))
                         ^ ((unsigned)((rr & 7) << 4));
            *(unsigned short*)(act_s + off) = f2bf(g);
        }
    }
    __syncthreads();

    // act -> A-frag registers (row = ln, k = s*32 + kg*8 + j)
    bf16x8 pa[2];
#pragma unroll
    for (int s = 0; s < 2; ++s) {
        unsigned off = ((unsigned)(ln * 128 + s * 64 + kg * 16))
                     ^ ((unsigned)((ln & 7) << 4));
        pa[s] = *(const bf16x8*)(act_s + off);
    }

    // ---------------- Phase 2: up GEMM, swapped operands ----------------
    // D[m][n]: m -> h offset (kg*4+r), n -> row (ln): lane-row-local f32x4
    const float* hvrow = hs  + (size_t)(wrow0 + ln) * 768 + kg * 4;
    float*       orow  = out + (size_t)(wrow0 + ln) * 768 + kg * 4;

#pragma unroll 4
    for (int n2 = 0; n2 < 12; ++n2) {
        const int ht = w * 12 + n2;                     // 0..47
        f32x4 a2 = (f32x4){0.f, 0.f, 0.f, 0.f};
#pragma unroll
        for (int s = 0; s < 2; ++s) {
            bf16x8 wfrag = *(const bf16x8*)(wuFrag + (s * 48 + ht) * 512 + lane * 8);
            a2 = __builtin_amdgcn_mfma_f32_16x16x32_bf16(wfrag, pa[s], a2, 0, 0, 0);
        }
        f32x4 hv = *(const f32x4*)(hvrow + ht * 16);
        f32x4 bu = *(const f32x4*)(b_up + ht * 16 + kg * 4);
        f32x4 o;
#pragma unroll
        for (int j = 0; j < 4; ++j) o[j] = a2[j] + hv[j] + bu[j];
        *(f32x4*)(orow + ht * 16) = o;
    }
}

extern "C" void kernel_launch(void* const* d_in, const int* in_sizes, int n_in,
                              void* d_out, int out_size, void* d_ws, size_t ws_size,
                              hipStream_t stream) {
    // dict order: hidden_states, b_down, b_up, d0,u0,d1,u1,d2,u2,d3,u3,d4,u4
    const float* hs = (const float*)d_in[0];
    const float* bd = (const float*)d_in[1];
    const float* bu = (const float*)d_in[2];
    const float* d0 = (const float*)d_in[3];
    const float* u0 = (const float*)d_in[4];
    const float* d1 = (const float*)d_in[5];
    const float* u1 = (const float*)d_in[6];
    const float* d2 = (const float*)d_in[7];
    const float* u2 = (const float*)d_in[8];
    const float* d3 = (const float*)d_in[9];
    const float* u3 = (const float*)d_in[10];
    const float* d4 = (const float*)d_in[11];
    const float* u4 = (const float*)d_in[12];

    unsigned short* wdFrag = (unsigned short*)d_ws;            // 49152 bf16
    unsigned short* wuFrag = wdFrag + 49152;                   // 49152 bf16

    tt_build_frags<<<384, 256, 0, stream>>>(d0, d1, d2, d3, d4,
                                            u0, u1, u2, u3, u4,
                                            wdFrag, wuFrag);

    const int rows = 16 * 2048;                // 32768 rows, 16 per block
    adapter_fused<<<rows / 16, 256, 0, stream>>>(hs, bd, bu, wdFrag, wuFrag,
                                                 (float*)d_out);
}

// Round 6
// 55.449 us; speedup vs baseline: 1.1904x; 1.1904x over previous
//
#include <hip/hip_runtime.h>
#include <hip/hip_bf16.h>

// ---------------------------------------------------------------------------
// TT-adapter fused kernel for MI355X (gfx950)
// out = hs + gelu(hs @ W_down + b_down) @ W_up + b_up
// W_down [768,64], W_up [64,768] reconstructed from rank-5 TT cores.
//
// Kernel 0: build bf16 weights in MFMA-fragment-ready layout in d_ws.
// Kernel 1: 2048 blocks x 256 thr (4 waves), 16 rows/block:
//   - hs tile staged fp32 into LDS via global_load_lds as TWO 24KB K-halves
//     (counted vmcnt: compute half 0 while half 1 is still in flight).
//   - Phase 1: down-GEMM K=768, col-split across waves (1 MFMA chain/wave).
//   - Phase 2: up-GEMM SWAPPED operands -> lane-row-local f32x4 epilogue:
//     residual from staged LDS + nontemporal f32x4 store.
// ---------------------------------------------------------------------------

typedef __attribute__((ext_vector_type(8))) short bf16x8;
typedef __attribute__((ext_vector_type(4))) float f32x4;

__device__ __forceinline__ unsigned short f2bf(float f) {
    union { float f; unsigned u; } v; v.f = f;
    unsigned r = (v.u + 0x7FFFu + ((v.u >> 16) & 1u)) >> 16;
    return (unsigned short)r;
}

// Staged TT contraction for one matrix entry (cores in LDS).
__device__ __forceinline__ float tt_entry(
    const float* c0, const float* c1, const float* c2,
    const float* c3, const float* c4,
    int i0, int i1, int i2, int i3, int i4)
{
    float v1[5], v2[5], v3[5];
#pragma unroll
    for (int r2 = 0; r2 < 5; ++r2) {
        float s = 0.f;
#pragma unroll
        for (int r1 = 0; r1 < 5; ++r1)
            s += c0[i0 * 5 + r1] * c1[(r1 * 8 + i1) * 5 + r2];
        v1[r2] = s;
    }
#pragma unroll
    for (int r3 = 0; r3 < 5; ++r3) {
        float s = 0.f;
#pragma unroll
        for (int r2 = 0; r2 < 5; ++r2)
            s += v1[r2] * c2[(r2 * 12 + i2) * 5 + r3];
        v2[r3] = s;
    }
#pragma unroll
    for (int r4 = 0; r4 < 5; ++r4) {
        float s = 0.f;
#pragma unroll
        for (int r3 = 0; r3 < 5; ++r3)
            s += v2[r3] * c3[(r3 * 8 + i3) * 5 + r4];
        v3[r4] = s;
    }
    float w = 0.f;
#pragma unroll
    for (int r4 = 0; r4 < 5; ++r4)
        w += v3[r4] * c4[r4 * 8 + i4];
    return w;
}

// WdFrag[((ks*4+nt)*64 + lane)*8 + j] = Wd[ks*32 + (lane>>4)*8 + j][nt*16 + (lane&15)]
// WuFrag[((s*48+ht)*64 + lane)*8 + j] = Wu[s*32  + (lane>>4)*8 + j][ht*16 + (lane&15)]
//   (B-frag of Wu == A-frag of Wu^T, so the same buffer serves the swapped GEMM)
__global__ __launch_bounds__(256) void tt_build_frags(
    const float* __restrict__ d0, const float* __restrict__ d1,
    const float* __restrict__ d2, const float* __restrict__ d3,
    const float* __restrict__ d4,
    const float* __restrict__ u0, const float* __restrict__ u1,
    const float* __restrict__ u2, const float* __restrict__ u3,
    const float* __restrict__ u4,
    unsigned short* __restrict__ wdFrag, unsigned short* __restrict__ wuFrag)
{
    __shared__ float cs[1560];
    {
        const float* srcs[10] = { d0, d1, d2, d3, d4, u0, u1, u2, u3, u4 };
        const int sizes[10]   = { 40, 200, 300, 200, 40, 40, 200, 300, 200, 40 };
        const int offs[10]    = { 0, 40, 240, 540, 740, 780, 820, 1020, 1320, 1520 };
#pragma unroll
        for (int c = 0; c < 10; ++c)
            for (int i = threadIdx.x; i < sizes[c]; i += 256)
                cs[offs[c] + i] = srcs[c][i];
    }
    __syncthreads();

    int e = blockIdx.x * 256 + threadIdx.x;   // 0..98303
    bool isUp = (e >= 49152);
    int idx = isUp ? (e - 49152) : e;
    int j    = idx & 7;
    int lane = (idx >> 3) & 63;
    int tile = idx >> 9;                      // 0..95
    int kg = lane >> 4, ln = lane & 15;

    if (!isUp) {
        int ks = tile >> 2, nt = tile & 3;
        int k = ks * 32 + kg * 8 + j;
        int a = nt * 16 + ln;
        int i0 = k / 96, i1 = (k / 12) % 8, i2 = k % 12;
        int i3 = a >> 3, i4 = a & 7;
        float w = tt_entry(cs + 0, cs + 40, cs + 240, cs + 540, cs + 740,
                           i0, i1, i2, i3, i4);
        wdFrag[idx] = f2bf(w);
    } else {
        int s = tile / 48, ht = tile % 48;
        int aIn = s * 32 + kg * 8 + j;
        int h = ht * 16 + ln;
        int i0 = aIn >> 3, i1 = aIn & 7;
        int i2 = h / 64, i3 = (h >> 3) & 7, i4 = h & 7;
        float w = tt_entry(cs + 780, cs + 820, cs + 1020, cs + 1320, cs + 1520,
                           i0, i1, i2, i3, i4);
        wuFrag[idx] = f2bf(w);
    }
}

__device__ __forceinline__ bf16x8 cvt8(f32x4 a, f32x4 b) {
    union { bf16x8 v; __hip_bfloat162 h[4]; } r;
    r.h[0] = __float22bfloat162_rn(make_float2(a[0], a[1]));
    r.h[1] = __float22bfloat162_rn(make_float2(a[2], a[3]));
    r.h[2] = __float22bfloat162_rn(make_float2(b[0], b[1]));
    r.h[3] = __float22bfloat162_rn(make_float2(b[2], b[3]));
    return r.v;
}

// ---------------------------------------------------------------------------
// hs_s layout: [half h][row 0..15][384 f32], half stride 24576 B, row stride
// 1536 B. Logical (h,row,cb) lives at physical h*24576 + row*1536 +
// (cb ^ ((row&7)<<4)). DMA writes linearly; source address carries the
// inverse (same) XOR. 16B-granular involution (XOR touches bits 4-6 only).
// ---------------------------------------------------------------------------
__global__ __launch_bounds__(256, 3) void adapter_fused(
    const float* __restrict__ hs,
    const float* __restrict__ b_down,
    const float* __restrict__ b_up,
    const unsigned short* __restrict__ wdFrag,
    const unsigned short* __restrict__ wuFrag,
    float* __restrict__ out)
{
    __shared__ char hs_s[49152];               // 2 x 24KB fp32 K-halves
    __shared__ char act_s[2048];               // bf16 16x64, XOR-swizzled

    const int t    = threadIdx.x;
    const int lane = t & 63;
    const int w    = t >> 6;
    const int ln   = lane & 15;
    const int kg   = lane >> 4;

    const int wrow0 = blockIdx.x * 16;
    const char* gbase = (const char*)(hs + (size_t)wrow0 * 768);

    // ---- issue ALL DMA: wave w covers rows w*4..w*4+3 of each half ----
#pragma unroll
    for (int h = 0; h < 2; ++h) {
#pragma unroll
        for (int jj = 0; jj < 6; ++jj) {
            int dl  = w * 6144 + jj * 1024 + lane * 16;     // within half
            int row = dl / 1536;
            int cbp = dl - row * 1536;
            int cb  = cbp ^ ((row & 7) << 4);
            __builtin_amdgcn_global_load_lds(
                (const __attribute__((address_space(1))) unsigned int*)
                    (gbase + (size_t)row * 3072 + h * 1536 + cb),
                (__attribute__((address_space(3))) unsigned int*)
                    (hs_s + h * 24576 + dl),
                16, 0, 0);
        }
    }

    // ---------------- Phase 1: down GEMM, col-split (nt = w) ----------------
    f32x4 acc = (f32x4){0.f, 0.f, 0.f, 0.f};
    const unsigned swz = (unsigned)((ln & 7) << 4);

    // wait half 0 only (6 DMA of half 1 still in flight), sync block
    asm volatile("s_waitcnt vmcnt(6)\n\ts_barrier" ::: "memory");

#pragma unroll 4
    for (int ks = 0; ks < 12; ++ks) {
        unsigned a0 = (unsigned)(ln * 1536) + (((unsigned)(ks * 128 + kg * 32)) ^ swz);
        f32x4 fa = *(const f32x4*)(hs_s + a0);
        f32x4 fb = *(const f32x4*)(hs_s + ((unsigned)(ln * 1536) +
                       (((unsigned)(ks * 128 + kg * 32 + 16)) ^ swz)));
        bf16x8 afrag = cvt8(fa, fb);
        bf16x8 bfrag = *(const bf16x8*)(wdFrag + (ks * 4 + w) * 512 + lane * 8);
        acc = __builtin_amdgcn_mfma_f32_16x16x32_bf16(afrag, bfrag, acc, 0, 0, 0);
    }

    // wait half 1, sync block
    asm volatile("s_waitcnt vmcnt(0)\n\ts_barrier" ::: "memory");

#pragma unroll 4
    for (int ks = 0; ks < 12; ++ks) {
        unsigned a0 = 24576u + (unsigned)(ln * 1536) +
                      (((unsigned)(ks * 128 + kg * 32)) ^ swz);
        f32x4 fa = *(const f32x4*)(hs_s + a0);
        f32x4 fb = *(const f32x4*)(hs_s + (24576u + (unsigned)(ln * 1536) +
                       (((unsigned)(ks * 128 + kg * 32 + 16)) ^ swz)));
        bf16x8 afrag = cvt8(fa, fb);
        bf16x8 bfrag = *(const bf16x8*)(wdFrag + ((12 + ks) * 4 + w) * 512 + lane * 8);
        acc = __builtin_amdgcn_mfma_f32_16x16x32_bf16(afrag, bfrag, acc, 0, 0, 0);
    }

    // bias + exact gelu -> act_s (bf16, XOR-swizzled rows)
    {
        const float bd = b_down[w * 16 + ln];
#pragma unroll
        for (int r = 0; r < 4; ++r) {
            const int rr = kg * 4 + r;                  // act row (local)
            float x = acc[r] + bd;
            float g = 0.5f * x * (1.0f + erff(x * 0.70710678118654752f));
            unsigned off = ((unsigned)(rr * 128 + (w * 16 + ln) * 2))
                         ^ ((unsigned)((rr & 7) << 4));
            *(unsigned short*)(act_s + off) = f2bf(g);
        }
    }
    __syncthreads();

    // act -> A-frag registers (row = ln, k = s*32 + kg*8 + j)
    bf16x8 pa[2];
#pragma unroll
    for (int s = 0; s < 2; ++s) {
        unsigned off = ((unsigned)(ln * 128 + s * 64 + kg * 16)) ^ swz;
        pa[s] = *(const bf16x8*)(act_s + off);
    }

    // ---------------- Phase 2: up GEMM, swapped operands ----------------
    // D[m][n]: m -> h offset (kg*4+r), n -> row (ln): lane-row-local f32x4
    float* orow = out + (size_t)(wrow0 + ln) * 768 + kg * 4;

#pragma unroll 4
    for (int n2 = 0; n2 < 12; ++n2) {
        const int ht = w * 12 + n2;                     // 0..47
        f32x4 a2 = (f32x4){0.f, 0.f, 0.f, 0.f};
#pragma unroll
        for (int s = 0; s < 2; ++s) {
            bf16x8 wfrag = *(const bf16x8*)(wuFrag + (s * 48 + ht) * 512 + lane * 8);
            a2 = __builtin_amdgcn_mfma_f32_16x16x32_bf16(wfrag, pa[s], a2, 0, 0, 0);
        }
        // residual from staged LDS: row ln, global col-byte g = ht*64 + kg*16
        const int g  = ht * 64 + kg * 16;
        const int h2 = (g >= 1536) ? 1 : 0;
        const int cb = g - h2 * 1536;
        unsigned roff = (unsigned)(h2 * 24576 + ln * 1536) + (((unsigned)cb) ^ swz);
        f32x4 hv = *(const f32x4*)(hs_s + roff);
        f32x4 bu = *(const f32x4*)(b_up + ht * 16 + kg * 4);
        f32x4 o;
#pragma unroll
        for (int j = 0; j < 4; ++j) o[j] = a2[j] + hv[j] + bu[j];
        __builtin_nontemporal_store(o, (f32x4*)(orow + ht * 16));
    }
}

extern "C" void kernel_launch(void* const* d_in, const int* in_sizes, int n_in,
                              void* d_out, int out_size, void* d_ws, size_t ws_size,
                              hipStream_t stream) {
    // dict order: hidden_states, b_down, b_up, d0,u0,d1,u1,d2,u2,d3,u3,d4,u4
    const float* hs = (const float*)d_in[0];
    const float* bd = (const float*)d_in[1];
    const float* bu = (const float*)d_in[2];
    const float* d0 = (const float*)d_in[3];
    const float* u0 = (const float*)d_in[4];
    const float* d1 = (const float*)d_in[5];
    const float* u1 = (const float*)d_in[6];
    const float* d2 = (const float*)d_in[7];
    const float* u2 = (const float*)d_in[8];
    const float* d3 = (const float*)d_in[9];
    const float* u3 = (const float*)d_in[10];
    const float* d4 = (const float*)d_in[11];
    const float* u4 = (const float*)d_in[12];

    unsigned short* wdFrag = (unsigned short*)d_ws;            // 49152 bf16
    unsigned short* wuFrag = wdFrag + 49152;                   // 49152 bf16

    tt_build_frags<<<384, 256, 0, stream>>>(d0, d1, d2, d3, d4,
                                            u0, u1, u2, u3, u4,
                                            wdFrag, wuFrag);

    const int rows = 16 * 2048;                // 32768 rows, 16 per block
    adapter_fused<<<rows / 16, 256, 0, stream>>>(hs, bd, bu, wdFrag, wuFrag,
                                                 (float*)d_out);
}

// Round 7
// 53.768 us; speedup vs baseline: 1.2276x; 1.0313x over previous
//
#include <hip/hip_runtime.h>
#include <hip/hip_bf16.h>

// ---------------------------------------------------------------------------
// TT-adapter fused kernel for MI355X (gfx950)
// out = hs + gelu(hs @ W_down + b_down) @ W_up + b_up
// W_down [768,64], W_up [64,768] reconstructed from rank-5 TT cores.
//
// Kernel 0: build bf16 weights in MFMA-fragment-ready layout in d_ws.
// Kernel 1: 2048 blocks x 256 thr (4 waves), 16 rows/block:
//   - phase-1 B-fragments preloaded to VGPR BEFORE the DMA issue, so the
//     counted vmcnt(6) really leaves half-1 DMAs in flight during half-0
//     compute (vmcnt retires in order!).
//   - hs tile staged fp32 into LDS via global_load_lds, two 24KB K-halves.
//   - Phase 1: down-GEMM K=768, col-split across waves (1 MFMA chain/wave).
//   - Phase 2: up-GEMM SWAPPED operands -> lane-row-local f32x4 epilogue:
//     residual from staged LDS + plain f32x4 store (NT store caused 1.4x
//     write amplification in R6).
// ---------------------------------------------------------------------------

typedef __attribute__((ext_vector_type(8))) short bf16x8;
typedef __attribute__((ext_vector_type(4))) float f32x4;

__device__ __forceinline__ unsigned short f2bf(float f) {
    union { float f; unsigned u; } v; v.f = f;
    unsigned r = (v.u + 0x7FFFu + ((v.u >> 16) & 1u)) >> 16;
    return (unsigned short)r;
}

// Staged TT contraction for one matrix entry (cores in LDS).
__device__ __forceinline__ float tt_entry(
    const float* c0, const float* c1, const float* c2,
    const float* c3, const float* c4,
    int i0, int i1, int i2, int i3, int i4)
{
    float v1[5], v2[5], v3[5];
#pragma unroll
    for (int r2 = 0; r2 < 5; ++r2) {
        float s = 0.f;
#pragma unroll
        for (int r1 = 0; r1 < 5; ++r1)
            s += c0[i0 * 5 + r1] * c1[(r1 * 8 + i1) * 5 + r2];
        v1[r2] = s;
    }
#pragma unroll
    for (int r3 = 0; r3 < 5; ++r3) {
        float s = 0.f;
#pragma unroll
        for (int r2 = 0; r2 < 5; ++r2)
            s += v1[r2] * c2[(r2 * 12 + i2) * 5 + r3];
        v2[r3] = s;
    }
#pragma unroll
    for (int r4 = 0; r4 < 5; ++r4) {
        float s = 0.f;
#pragma unroll
        for (int r3 = 0; r3 < 5; ++r3)
            s += v2[r3] * c3[(r3 * 8 + i3) * 5 + r4];
        v3[r4] = s;
    }
    float w = 0.f;
#pragma unroll
    for (int r4 = 0; r4 < 5; ++r4)
        w += v3[r4] * c4[r4 * 8 + i4];
    return w;
}

// WdFrag[((ks*4+nt)*64 + lane)*8 + j] = Wd[ks*32 + (lane>>4)*8 + j][nt*16 + (lane&15)]
// WuFrag[((s*48+ht)*64 + lane)*8 + j] = Wu[s*32  + (lane>>4)*8 + j][ht*16 + (lane&15)]
//   (B-frag of Wu == A-frag of Wu^T, so the same buffer serves the swapped GEMM)
__global__ __launch_bounds__(256) void tt_build_frags(
    const float* __restrict__ d0, const float* __restrict__ d1,
    const float* __restrict__ d2, const float* __restrict__ d3,
    const float* __restrict__ d4,
    const float* __restrict__ u0, const float* __restrict__ u1,
    const float* __restrict__ u2, const float* __restrict__ u3,
    const float* __restrict__ u4,
    unsigned short* __restrict__ wdFrag, unsigned short* __restrict__ wuFrag)
{
    __shared__ float cs[1560];
    {
        const float* srcs[10] = { d0, d1, d2, d3, d4, u0, u1, u2, u3, u4 };
        const int sizes[10]   = { 40, 200, 300, 200, 40, 40, 200, 300, 200, 40 };
        const int offs[10]    = { 0, 40, 240, 540, 740, 780, 820, 1020, 1320, 1520 };
#pragma unroll
        for (int c = 0; c < 10; ++c)
            for (int i = threadIdx.x; i < sizes[c]; i += 256)
                cs[offs[c] + i] = srcs[c][i];
    }
    __syncthreads();

    int e = blockIdx.x * 256 + threadIdx.x;   // 0..98303
    bool isUp = (e >= 49152);
    int idx = isUp ? (e - 49152) : e;
    int j    = idx & 7;
    int lane = (idx >> 3) & 63;
    int tile = idx >> 9;                      // 0..95
    int kg = lane >> 4, ln = lane & 15;

    if (!isUp) {
        int ks = tile >> 2, nt = tile & 3;
        int k = ks * 32 + kg * 8 + j;
        int a = nt * 16 + ln;
        int i0 = k / 96, i1 = (k / 12) % 8, i2 = k % 12;
        int i3 = a >> 3, i4 = a & 7;
        float w = tt_entry(cs + 0, cs + 40, cs + 240, cs + 540, cs + 740,
                           i0, i1, i2, i3, i4);
        wdFrag[idx] = f2bf(w);
    } else {
        int s = tile / 48, ht = tile % 48;
        int aIn = s * 32 + kg * 8 + j;
        int h = ht * 16 + ln;
        int i0 = aIn >> 3, i1 = aIn & 7;
        int i2 = h / 64, i3 = (h >> 3) & 7, i4 = h & 7;
        float w = tt_entry(cs + 780, cs + 820, cs + 1020, cs + 1320, cs + 1520,
                           i0, i1, i2, i3, i4);
        wuFrag[idx] = f2bf(w);
    }
}

__device__ __forceinline__ bf16x8 cvt8(f32x4 a, f32x4 b) {
    union { bf16x8 v; __hip_bfloat162 h[4]; } r;
    r.h[0] = __float22bfloat162_rn(make_float2(a[0], a[1]));
    r.h[1] = __float22bfloat162_rn(make_float2(a[2], a[3]));
    r.h[2] = __float22bfloat162_rn(make_float2(b[0], b[1]));
    r.h[3] = __float22bfloat162_rn(make_float2(b[2], b[3]));
    return r.v;
}

// ---------------------------------------------------------------------------
// hs_s layout: [half h][row 0..15][384 f32], half stride 24576 B, row stride
// 1536 B. Logical (h,row,cb) lives at physical h*24576 + row*1536 +
// (cb ^ ((row&7)<<4)). DMA writes linearly; source address carries the
// inverse (same) XOR. 16B-granular involution (XOR touches bits 4-6 only).
//
// VMEM issue order per wave (vmcnt retires IN ORDER):
//   [bfr0 x12 global] [DMA x12] ...vmcnt(6) => bfr0 + half-0 DMA complete,
//   half-1 DMA (6) still outstanding during half-0 compute (pure LDS+VGPR).
//   [bfr1 x12 global] issued after the wait; drained by vmcnt(0) with half-1.
// ---------------------------------------------------------------------------
__global__ __launch_bounds__(256, 3) void adapter_fused(
    const float* __restrict__ hs,
    const float* __restrict__ b_down,
    const float* __restrict__ b_up,
    const unsigned short* __restrict__ wdFrag,
    const unsigned short* __restrict__ wuFrag,
    float* __restrict__ out)
{
    __shared__ char hs_s[49152];               // 2 x 24KB fp32 K-halves
    __shared__ char act_s[2048];               // bf16 16x64, XOR-swizzled

    const int t    = threadIdx.x;
    const int lane = t & 63;
    const int w    = t >> 6;
    const int ln   = lane & 15;
    const int kg   = lane >> 4;

    const int wrow0 = blockIdx.x * 16;
    const char* gbase = (const char*)(hs + (size_t)wrow0 * 768);

    // ---- preload half-0 B-fragments (BEFORE the DMAs, so vmcnt counting
    //      lets half-1 DMAs stay in flight through half-0 compute) ----
    bf16x8 bfr0[12];
#pragma unroll
    for (int ks = 0; ks < 12; ++ks)
        bfr0[ks] = *(const bf16x8*)(wdFrag + (ks * 4 + w) * 512 + lane * 8);
    __builtin_amdgcn_sched_barrier(0);

    // ---- issue ALL DMA: wave w covers rows w*4..w*4+3 of each half ----
#pragma unroll
    for (int h = 0; h < 2; ++h) {
#pragma unroll
        for (int jj = 0; jj < 6; ++jj) {
            int dl  = w * 6144 + jj * 1024 + lane * 16;     // within half
            int row = dl / 1536;
            int cbp = dl - row * 1536;
            int cb  = cbp ^ ((row & 7) << 4);
            __builtin_amdgcn_global_load_lds(
                (const __attribute__((address_space(1))) unsigned int*)
                    (gbase + (size_t)row * 3072 + h * 1536 + cb),
                (__attribute__((address_space(3))) unsigned int*)
                    (hs_s + h * 24576 + dl),
                16, 0, 0);
        }
    }
    __builtin_amdgcn_sched_barrier(0);

    // ---------------- Phase 1: down GEMM, col-split (nt = w) ----------------
    f32x4 acc = (f32x4){0.f, 0.f, 0.f, 0.f};
    const unsigned swz = (unsigned)((ln & 7) << 4);

    // wait: bfr0 + half-0 DMA done; 6 half-1 DMAs still outstanding
    asm volatile("s_waitcnt vmcnt(6)\n\ts_barrier" ::: "memory");
    __builtin_amdgcn_sched_barrier(0);

    // preload half-1 B-fragments (in flight during half-0 compute)
    bf16x8 bfr1[12];
#pragma unroll
    for (int ks = 0; ks < 12; ++ks)
        bfr1[ks] = *(const bf16x8*)(wdFrag + ((12 + ks) * 4 + w) * 512 + lane * 8);

#pragma unroll
    for (int ks = 0; ks < 12; ++ks) {
        unsigned a0 = (unsigned)(ln * 1536) + (((unsigned)(ks * 128 + kg * 32)) ^ swz);
        f32x4 fa = *(const f32x4*)(hs_s + a0);
        f32x4 fb = *(const f32x4*)(hs_s + ((unsigned)(ln * 1536) +
                       (((unsigned)(ks * 128 + kg * 32 + 16)) ^ swz)));
        bf16x8 afrag = cvt8(fa, fb);
        acc = __builtin_amdgcn_mfma_f32_16x16x32_bf16(afrag, bfr0[ks], acc, 0, 0, 0);
    }

    // wait: half-1 DMA + bfr1 done
    asm volatile("s_waitcnt vmcnt(0)\n\ts_barrier" ::: "memory");
    __builtin_amdgcn_sched_barrier(0);

#pragma unroll
    for (int ks = 0; ks < 12; ++ks) {
        unsigned a0 = 24576u + (unsigned)(ln * 1536) +
                      (((unsigned)(ks * 128 + kg * 32)) ^ swz);
        f32x4 fa = *(const f32x4*)(hs_s + a0);
        f32x4 fb = *(const f32x4*)(hs_s + (24576u + (unsigned)(ln * 1536) +
                       (((unsigned)(ks * 128 + kg * 32 + 16)) ^ swz)));
        bf16x8 afrag = cvt8(fa, fb);
        acc = __builtin_amdgcn_mfma_f32_16x16x32_bf16(afrag, bfr1[ks], acc, 0, 0, 0);
    }

    // bias + exact gelu -> act_s (bf16, XOR-swizzled rows)
    {
        const float bd = b_down[w * 16 + ln];
#pragma unroll
        for (int r = 0; r < 4; ++r) {
            const int rr = kg * 4 + r;                  // act row (local)
            float x = acc[r] + bd;
            float g = 0.5f * x * (1.0f + erff(x * 0.70710678118654752f));
            unsigned off = ((unsigned)(rr * 128 + (w * 16 + ln) * 2))
                         ^ ((unsigned)((rr & 7) << 4));
            *(unsigned short*)(act_s + off) = f2bf(g);
        }
    }
    __syncthreads();

    // act -> A-frag registers (row = ln, k = s*32 + kg*8 + j)
    bf16x8 pa[2];
#pragma unroll
    for (int s = 0; s < 2; ++s) {
        unsigned off = ((unsigned)(ln * 128 + s * 64 + kg * 16)) ^ swz;
        pa[s] = *(const bf16x8*)(act_s + off);
    }

    // ---------------- Phase 2: up GEMM, swapped operands ----------------
    // D[m][n]: m -> h offset (kg*4+r), n -> row (ln): lane-row-local f32x4
    float* orow = out + (size_t)(wrow0 + ln) * 768 + kg * 4;

#pragma unroll 4
    for (int n2 = 0; n2 < 12; ++n2) {
        const int ht = w * 12 + n2;                     // 0..47
        f32x4 a2 = (f32x4){0.f, 0.f, 0.f, 0.f};
#pragma unroll
        for (int s = 0; s < 2; ++s) {
            bf16x8 wfrag = *(const bf16x8*)(wuFrag + (s * 48 + ht) * 512 + lane * 8);
            a2 = __builtin_amdgcn_mfma_f32_16x16x32_bf16(wfrag, pa[s], a2, 0, 0, 0);
        }
        // residual from staged LDS: row ln, global col-byte g = ht*64 + kg*16
        const int g  = ht * 64 + kg * 16;
        const int h2 = (g >= 1536) ? 1 : 0;
        const int cb = g - h2 * 1536;
        unsigned roff = (unsigned)(h2 * 24576 + ln * 1536) + (((unsigned)cb) ^ swz);
        f32x4 hv = *(const f32x4*)(hs_s + roff);
        f32x4 bu = *(const f32x4*)(b_up + ht * 16 + kg * 4);
        f32x4 o;
#pragma unroll
        for (int j = 0; j < 4; ++j) o[j] = a2[j] + hv[j] + bu[j];
        *(f32x4*)(orow + ht * 16) = o;
    }
}

extern "C" void kernel_launch(void* const* d_in, const int* in_sizes, int n_in,
                              void* d_out, int out_size, void* d_ws, size_t ws_size,
                              hipStream_t stream) {
    // dict order: hidden_states, b_down, b_up, d0,u0,d1,u1,d2,u2,d3,u3,d4,u4
    const float* hs = (const float*)d_in[0];
    const float* bd = (const float*)d_in[1];
    const float* bu = (const float*)d_in[2];
    const float* d0 = (const float*)d_in[3];
    const float* u0 = (const float*)d_in[4];
    const float* d1 = (const float*)d_in[5];
    const float* u1 = (const float*)d_in[6];
    const float* d2 = (const float*)d_in[7];
    const float* u2 = (const float*)d_in[8];
    const float* d3 = (const float*)d_in[9];
    const float* u3 = (const float*)d_in[10];
    const float* d4 = (const float*)d_in[11];
    const float* u4 = (const float*)d_in[12];

    unsigned short* wdFrag = (unsigned short*)d_ws;            // 49152 bf16
    unsigned short* wuFrag = wdFrag + 49152;                   // 49152 bf16

    tt_build_frags<<<384, 256, 0, stream>>>(d0, d1, d2, d3, d4,
                                            u0, u1, u2, u3, u4,
                                            wdFrag, wuFrag);

    const int rows = 16 * 2048;                // 32768 rows, 16 per block
    adapter_fused<<<rows / 16, 256, 0, stream>>>(hs, bd, bu, wdFrag, wuFrag,
                                                 (float*)d_out);
}

// Round 8
// 49.951 us; speedup vs baseline: 1.3215x; 1.0764x over previous
//
#include <hip/hip_runtime.h>
#include <hip/hip_bf16.h>

// ---------------------------------------------------------------------------
// TT-adapter fused kernel for MI355X (gfx950)
// out = hs + gelu(hs @ W_down + b_down) @ W_up + b_up
// W_down [768,64], W_up [64,768] reconstructed from rank-5 TT cores.
//
// Kernel 0: build bf16 weights in MFMA-fragment-ready layout in d_ws.
// Kernel 1: 2048 blocks x 256 thr (4 waves), 16 rows/block:
//   - B-fragments preloaded to VGPR BEFORE the DMA issue so counted vmcnt(6)
//     overlaps half-1 DMA with half-0 compute (vmcnt retires in order).
//   - hs staged fp32 into LDS via global_load_lds, two 24KB K-halves.
//   - Phase 1: down-GEMM K=768, col-split across waves.
//   - Phase 2: up-GEMM swapped operands; residual+bias added IN PLACE in
//     hs_s (no global stores here -> no partial-line RFO traffic).
//   - Bulk store: row-contiguous 1KB-per-instruction stores (full 128B
//     lines only; kills the 50MB write-allocate FETCH seen in R7).
// ---------------------------------------------------------------------------

typedef __attribute__((ext_vector_type(8))) short bf16x8;
typedef __attribute__((ext_vector_type(4))) float f32x4;

__device__ __forceinline__ unsigned short f2bf(float f) {
    union { float f; unsigned u; } v; v.f = f;
    unsigned r = (v.u + 0x7FFFu + ((v.u >> 16) & 1u)) >> 16;
    return (unsigned short)r;
}

// Staged TT contraction for one matrix entry (cores in LDS).
__device__ __forceinline__ float tt_entry(
    const float* c0, const float* c1, const float* c2,
    const float* c3, const float* c4,
    int i0, int i1, int i2, int i3, int i4)
{
    float v1[5], v2[5], v3[5];
#pragma unroll
    for (int r2 = 0; r2 < 5; ++r2) {
        float s = 0.f;
#pragma unroll
        for (int r1 = 0; r1 < 5; ++r1)
            s += c0[i0 * 5 + r1] * c1[(r1 * 8 + i1) * 5 + r2];
        v1[r2] = s;
    }
#pragma unroll
    for (int r3 = 0; r3 < 5; ++r3) {
        float s = 0.f;
#pragma unroll
        for (int r2 = 0; r2 < 5; ++r2)
            s += v1[r2] * c2[(r2 * 12 + i2) * 5 + r3];
        v2[r3] = s;
    }
#pragma unroll
    for (int r4 = 0; r4 < 5; ++r4) {
        float s = 0.f;
#pragma unroll
        for (int r3 = 0; r3 < 5; ++r3)
            s += v2[r3] * c3[(r3 * 8 + i3) * 5 + r4];
        v3[r4] = s;
    }
    float w = 0.f;
#pragma unroll
    for (int r4 = 0; r4 < 5; ++r4)
        w += v3[r4] * c4[r4 * 8 + i4];
    return w;
}

// WdFrag[((ks*4+nt)*64 + lane)*8 + j] = Wd[ks*32 + (lane>>4)*8 + j][nt*16 + (lane&15)]
// WuFrag[((s*48+ht)*64 + lane)*8 + j] = Wu[s*32  + (lane>>4)*8 + j][ht*16 + (lane&15)]
//   (B-frag of Wu == A-frag of Wu^T, so the same buffer serves the swapped GEMM)
__global__ __launch_bounds__(256) void tt_build_frags(
    const float* __restrict__ d0, const float* __restrict__ d1,
    const float* __restrict__ d2, const float* __restrict__ d3,
    const float* __restrict__ d4,
    const float* __restrict__ u0, const float* __restrict__ u1,
    const float* __restrict__ u2, const float* __restrict__ u3,
    const float* __restrict__ u4,
    unsigned short* __restrict__ wdFrag, unsigned short* __restrict__ wuFrag)
{
    __shared__ float cs[1560];
    {
        const float* srcs[10] = { d0, d1, d2, d3, d4, u0, u1, u2, u3, u4 };
        const int sizes[10]   = { 40, 200, 300, 200, 40, 40, 200, 300, 200, 40 };
        const int offs[10]    = { 0, 40, 240, 540, 740, 780, 820, 1020, 1320, 1520 };
#pragma unroll
        for (int c = 0; c < 10; ++c)
            for (int i = threadIdx.x; i < sizes[c]; i += 256)
                cs[offs[c] + i] = srcs[c][i];
    }
    __syncthreads();

    int e = blockIdx.x * 256 + threadIdx.x;   // 0..98303
    bool isUp = (e >= 49152);
    int idx = isUp ? (e - 49152) : e;
    int j    = idx & 7;
    int lane = (idx >> 3) & 63;
    int tile = idx >> 9;                      // 0..95
    int kg = lane >> 4, ln = lane & 15;

    if (!isUp) {
        int ks = tile >> 2, nt = tile & 3;
        int k = ks * 32 + kg * 8 + j;
        int a = nt * 16 + ln;
        int i0 = k / 96, i1 = (k / 12) % 8, i2 = k % 12;
        int i3 = a >> 3, i4 = a & 7;
        float w = tt_entry(cs + 0, cs + 40, cs + 240, cs + 540, cs + 740,
                           i0, i1, i2, i3, i4);
        wdFrag[idx] = f2bf(w);
    } else {
        int s = tile / 48, ht = tile % 48;
        int aIn = s * 32 + kg * 8 + j;
        int h = ht * 16 + ln;
        int i0 = aIn >> 3, i1 = aIn & 7;
        int i2 = h / 64, i3 = (h >> 3) & 7, i4 = h & 7;
        float w = tt_entry(cs + 780, cs + 820, cs + 1020, cs + 1320, cs + 1520,
                           i0, i1, i2, i3, i4);
        wuFrag[idx] = f2bf(w);
    }
}

__device__ __forceinline__ bf16x8 cvt8(f32x4 a, f32x4 b) {
    union { bf16x8 v; __hip_bfloat162 h[4]; } r;
    r.h[0] = __float22bfloat162_rn(make_float2(a[0], a[1]));
    r.h[1] = __float22bfloat162_rn(make_float2(a[2], a[3]));
    r.h[2] = __float22bfloat162_rn(make_float2(b[0], b[1]));
    r.h[3] = __float22bfloat162_rn(make_float2(b[2], b[3]));
    return r.v;
}

// ---------------------------------------------------------------------------
// hs_s layout: [half h][row 0..15][384 f32], half stride 24576 B, row stride
// 1536 B. Logical (h,row,cb) lives at physical h*24576 + row*1536 +
// (cb ^ ((row&7)<<4)). DMA writes linearly; source address carries the same
// XOR (16B-granular involution, bits 4-6 only).
// ---------------------------------------------------------------------------
__global__ __launch_bounds__(256, 3) void adapter_fused(
    const float* __restrict__ hs,
    const float* __restrict__ b_down,
    const float* __restrict__ b_up,
    const unsigned short* __restrict__ wdFrag,
    const unsigned short* __restrict__ wuFrag,
    float* __restrict__ out)
{
    __shared__ char hs_s[49152];               // 2 x 24KB fp32 K-halves
    __shared__ char act_s[2048];               // bf16 16x64, XOR-swizzled

    const int t    = threadIdx.x;
    const int lane = t & 63;
    const int w    = t >> 6;
    const int ln   = lane & 15;
    const int kg   = lane >> 4;

    const int wrow0 = blockIdx.x * 16;
    const char* gbase = (const char*)(hs + (size_t)wrow0 * 768);

    // ---- preload half-0 B-fragments (BEFORE the DMAs, so vmcnt counting
    //      lets half-1 DMAs stay in flight through half-0 compute) ----
    bf16x8 bfr0[12];
#pragma unroll
    for (int ks = 0; ks < 12; ++ks)
        bfr0[ks] = *(const bf16x8*)(wdFrag + (ks * 4 + w) * 512 + lane * 8);
    __builtin_amdgcn_sched_barrier(0);

    // ---- issue ALL DMA: wave w covers rows w*4..w*4+3 of each half ----
#pragma unroll
    for (int h = 0; h < 2; ++h) {
#pragma unroll
        for (int jj = 0; jj < 6; ++jj) {
            int dl  = w * 6144 + jj * 1024 + lane * 16;     // within half
            int row = dl / 1536;
            int cbp = dl - row * 1536;
            int cb  = cbp ^ ((row & 7) << 4);
            __builtin_amdgcn_global_load_lds(
                (const __attribute__((address_space(1))) unsigned int*)
                    (gbase + (size_t)row * 3072 + h * 1536 + cb),
                (__attribute__((address_space(3))) unsigned int*)
                    (hs_s + h * 24576 + dl),
                16, 0, 0);
        }
    }
    __builtin_amdgcn_sched_barrier(0);

    // ---------------- Phase 1: down GEMM, col-split (nt = w) ----------------
    f32x4 acc = (f32x4){0.f, 0.f, 0.f, 0.f};
    const unsigned swz = (unsigned)((ln & 7) << 4);

    // wait: bfr0 + half-0 DMA done; 6 half-1 DMAs still outstanding
    asm volatile("s_waitcnt vmcnt(6)\n\ts_barrier" ::: "memory");
    __builtin_amdgcn_sched_barrier(0);

    // preload half-1 B-fragments (in flight during half-0 compute)
    bf16x8 bfr1[12];
#pragma unroll
    for (int ks = 0; ks < 12; ++ks)
        bfr1[ks] = *(const bf16x8*)(wdFrag + ((12 + ks) * 4 + w) * 512 + lane * 8);

#pragma unroll
    for (int ks = 0; ks < 12; ++ks) {
        unsigned a0 = (unsigned)(ln * 1536) + (((unsigned)(ks * 128 + kg * 32)) ^ swz);
        f32x4 fa = *(const f32x4*)(hs_s + a0);
        f32x4 fb = *(const f32x4*)(hs_s + ((unsigned)(ln * 1536) +
                       (((unsigned)(ks * 128 + kg * 32 + 16)) ^ swz)));
        bf16x8 afrag = cvt8(fa, fb);
        acc = __builtin_amdgcn_mfma_f32_16x16x32_bf16(afrag, bfr0[ks], acc, 0, 0, 0);
    }

    // wait: half-1 DMA + bfr1 done
    asm volatile("s_waitcnt vmcnt(0)\n\ts_barrier" ::: "memory");
    __builtin_amdgcn_sched_barrier(0);

#pragma unroll
    for (int ks = 0; ks < 12; ++ks) {
        unsigned a0 = 24576u + (unsigned)(ln * 1536) +
                      (((unsigned)(ks * 128 + kg * 32)) ^ swz);
        f32x4 fa = *(const f32x4*)(hs_s + a0);
        f32x4 fb = *(const f32x4*)(hs_s + (24576u + (unsigned)(ln * 1536) +
                       (((unsigned)(ks * 128 + kg * 32 + 16)) ^ swz)));
        bf16x8 afrag = cvt8(fa, fb);
        acc = __builtin_amdgcn_mfma_f32_16x16x32_bf16(afrag, bfr1[ks], acc, 0, 0, 0);
    }

    // bias + exact gelu -> act_s (bf16, XOR-swizzled rows)
    {
        const float bd = b_down[w * 16 + ln];
#pragma unroll
        for (int r = 0; r < 4; ++r) {
            const int rr = kg * 4 + r;                  // act row (local)
            float x = acc[r] + bd;
            float g = 0.5f * x * (1.0f + erff(x * 0.70710678118654752f));
            unsigned off = ((unsigned)(rr * 128 + (w * 16 + ln) * 2))
                         ^ ((unsigned)((rr & 7) << 4));
            *(unsigned short*)(act_s + off) = f2bf(g);
        }
    }
    __syncthreads();

    // act -> A-frag registers (row = ln, k = s*32 + kg*8 + j)
    bf16x8 pa[2];
#pragma unroll
    for (int s = 0; s < 2; ++s) {
        unsigned off = ((unsigned)(ln * 128 + s * 64 + kg * 16)) ^ swz;
        pa[s] = *(const bf16x8*)(act_s + off);
    }

    // ---------------- Phase 2: up GEMM, swapped operands ----------------
    // D[m][n]: m -> h offset (kg*4+r), n -> row (ln). Residual+bias added
    // IN PLACE in hs_s (wave w exclusively owns h-range [w*192,(w+1)*192)).
#pragma unroll 4
    for (int n2 = 0; n2 < 12; ++n2) {
        const int ht = w * 12 + n2;                     // 0..47
        f32x4 a2 = (f32x4){0.f, 0.f, 0.f, 0.f};
#pragma unroll
        for (int s = 0; s < 2; ++s) {
            bf16x8 wfrag = *(const bf16x8*)(wuFrag + (s * 48 + ht) * 512 + lane * 8);
            a2 = __builtin_amdgcn_mfma_f32_16x16x32_bf16(wfrag, pa[s], a2, 0, 0, 0);
        }
        // row ln, global col-byte g = ht*64 + kg*16
        const int g  = ht * 64 + kg * 16;
        const int h2 = (g >= 1536) ? 1 : 0;
        const int cb = g - h2 * 1536;
        unsigned roff = (unsigned)(h2 * 24576 + ln * 1536) + (((unsigned)cb) ^ swz);
        f32x4 hv = *(const f32x4*)(hs_s + roff);
        f32x4 bu = *(const f32x4*)(b_up + ht * 16 + kg * 4);
        f32x4 o;
#pragma unroll
        for (int j = 0; j < 4; ++j) o[j] = a2[j] + hv[j] + bu[j];
        *(f32x4*)(hs_s + roff) = o;                     // in-place, no RFO
    }
    __syncthreads();

    // ---------------- Bulk store: full-line row-contiguous ----------------
    // Wave w stores rows w*4..w*4+3; each instruction = 1KB of ONE row.
    {
        char* obase = (char*)out + (size_t)wrow0 * 3072;
#pragma unroll
        for (int rr = 0; rr < 4; ++rr) {
            const int row = w * 4 + rr;
            const unsigned rswz = (unsigned)((row & 7) << 4);
#pragma unroll
            for (int c = 0; c < 3; ++c) {
                const int cbf = c * 1024 + lane * 16;   // byte col in row
                const int hh  = (cbf >= 1536) ? 1 : 0;
                const int cbh = cbf - hh * 1536;
                f32x4 v = *(const f32x4*)(hs_s + hh * 24576 + row * 1536
                                          + (((unsigned)cbh) ^ rswz));
                *(f32x4*)(obase + (size_t)row * 3072 + cbf) = v;
            }
        }
    }
}

extern "C" void kernel_launch(void* const* d_in, const int* in_sizes, int n_in,
                              void* d_out, int out_size, void* d_ws, size_t ws_size,
                              hipStream_t stream) {
    // dict order: hidden_states, b_down, b_up, d0,u0,d1,u1,d2,u2,d3,u3,d4,u4
    const float* hs = (const float*)d_in[0];
    const float* bd = (const float*)d_in[1];
    const float* bu = (const float*)d_in[2];
    const float* d0 = (const float*)d_in[3];
    const float* u0 = (const float*)d_in[4];
    const float* d1 = (const float*)d_in[5];
    const float* u1 = (const float*)d_in[6];
    const float* d2 = (const float*)d_in[7];
    const float* u2 = (const float*)d_in[8];
    const float* d3 = (const float*)d_in[9];
    const float* u3 = (const float*)d_in[10];
    const float* d4 = (const float*)d_in[11];
    const float* u4 = (const float*)d_in[12];

    unsigned short* wdFrag = (unsigned short*)d_ws;            // 49152 bf16
    unsigned short* wuFrag = wdFrag + 49152;                   // 49152 bf16

    tt_build_frags<<<384, 256, 0, stream>>>(d0, d1, d2, d3, d4,
                                            u0, u1, u2, u3, u4,
                                            wdFrag, wuFrag);

    const int rows = 16 * 2048;                // 32768 rows, 16 per block
    adapter_fused<<<rows / 16, 256, 0, stream>>>(hs, bd, bu, wdFrag, wuFrag,
                                                 (float*)d_out);
}